// Round 2
// baseline (61.239 us; speedup 1.0000x reference)
//
#include <hip/hip_runtime.h>

// YOLOv1 loss, forward only. preds/targets: (16384,7,7,30) f32 -> scalar f32.
// Per cell: coo=(T4>0), noo=(T4==0)
//   noobj   = noo * ((P4-T4)^2 + (P9-T9)^2)
//   iou_b   = IoU(pred box b, pred box 0)   (reference quirk: tbox = pred box 0)
//   idx     = argmax(iou)  [np semantics: first max; NaN acts as max]
//   contain = coo * (P[5i+4] - max_iou)^2 ; ncl = coo * P[5(1-i)+4]^2
//   loss += contain + 0.5*ncl + 0.5*noobj   (loc_loss, class_loss are exactly 0)
// total = sum / 16384
//
// R1: stage full 256-cell tiles of preds AND targets into LDS via coalesced
// float4 streams (R0 was request-bound: 120B-stride scattered loads, 1.4 TB/s).

#define TILE 256           // cells per block
#define TFLOATS (TILE*30)  // 7680 floats per array tile

__global__ __launch_bounds__(256) void yolo_loss_kernel(
    const float* __restrict__ preds,
    const float* __restrict__ targets,
    float* __restrict__ out,
    int ncells)
{
    __shared__ float sp[TFLOATS];
    __shared__ float st[TFLOATS];
    __shared__ float warp_sums[4];

    const int tid = threadIdx.x;
    const long tile0 = (long)blockIdx.x * TILE;
    const long fbase = tile0 * 30;
    const int cells = min(TILE, ncells - (int)tile0);

    if (cells == TILE) {
        // full tile: 7680 floats = 1920 float4 per array, base is 16B-aligned
        const float4* gp = reinterpret_cast<const float4*>(preds + fbase);
        const float4* gt = reinterpret_cast<const float4*>(targets + fbase);
        float4* lp = reinterpret_cast<float4*>(sp);
        float4* lt = reinterpret_cast<float4*>(st);
        #pragma unroll
        for (int i = 0; i < TFLOATS / 4; i += 256) {
            int j = i + tid;
            if (j < TFLOATS / 4) {
                lp[j] = gp[j];
                lt[j] = gt[j];
            }
        }
    } else {
        for (int j = tid; j < cells * 30; j += 256) {
            sp[j] = preds[fbase + j];
            st[j] = targets[fbase + j];
        }
    }
    __syncthreads();

    float contrib = 0.0f;
    if (tid < cells) {
        const float* p = sp + tid * 30;
        float t4 = st[tid * 30 + 4];
        float t9 = st[tid * 30 + 9];

        float coo = (t4 > 0.0f) ? 1.0f : 0.0f;
        float noo = (t4 == 0.0f) ? 1.0f : 0.0f;

        float d4 = p[4] - t4;
        float d9 = p[9] - t9;
        float noo_term = noo * (d4 * d4 + d9 * d9);

        // "target" box for IoU = pred box 0 (reference quirk)
        float lt2x = p[0] / 14.0f - 0.5f * p[2];
        float lt2y = p[1] / 14.0f - 0.5f * p[3];
        float rb2x = p[0] / 14.0f + 0.5f * p[2];
        float rb2y = p[1] / 14.0f + 0.5f * p[3];
        float area2 = (rb2x - lt2x) * (rb2y - lt2y);

        float iou[2];
        #pragma unroll
        for (int b = 0; b < 2; ++b) {
            float x = p[5 * b] / 14.0f;
            float y = p[5 * b + 1] / 14.0f;
            float w = p[5 * b + 2];
            float h = p[5 * b + 3];
            float lt1x = x - 0.5f * w, lt1y = y - 0.5f * h;
            float rb1x = x + 0.5f * w, rb1y = y + 0.5f * h;
            float iltx = fmaxf(lt1x, lt2x), ilty = fmaxf(lt1y, lt2y);
            float irbx = fminf(rb1x, rb2x), irby = fminf(rb1y, rb2y);
            float iwx = fmaxf(irbx - iltx, 0.0f);
            float iwy = fmaxf(irby - ilty, 0.0f);
            float inter = iwx * iwy;
            float area1 = (rb1x - lt1x) * (rb1y - lt1y);
            iou[b] = inter / (area1 + area2 - inter);
        }

        // np.argmax semantics: first occurrence of max; NaN compares as maximum.
        int idx;
        float max_iou;
        if (isnan(iou[0]))      { idx = 0; max_iou = iou[0]; }
        else if (isnan(iou[1])) { idx = 1; max_iou = iou[1]; }
        else                    { idx = (iou[1] > iou[0]) ? 1 : 0;
                                  max_iou = fmaxf(iou[0], iou[1]); }

        float resp4  = p[5 * idx + 4];
        float nresp4 = p[5 * (1 - idx) + 4];
        float cdiff  = resp4 - max_iou;

        contrib = coo * (cdiff * cdiff + 0.5f * nresp4 * nresp4) + 0.5f * noo_term;
    }

    // wave (64-lane) shuffle reduce
    #pragma unroll
    for (int off = 32; off > 0; off >>= 1)
        contrib += __shfl_down(contrib, off, 64);

    int lane = tid & 63;
    int wid  = tid >> 6;
    if (lane == 0) warp_sums[wid] = contrib;
    __syncthreads();

    if (tid == 0) {
        float s = warp_sums[0] + warp_sums[1] + warp_sums[2] + warp_sums[3];
        atomicAdd(out, s * (1.0f / 16384.0f));
    }
}

extern "C" void kernel_launch(void* const* d_in, const int* in_sizes, int n_in,
                              void* d_out, int out_size, void* d_ws, size_t ws_size,
                              hipStream_t stream) {
    const float* preds   = (const float*)d_in[0];
    const float* targets = (const float*)d_in[1];
    float* out = (float*)d_out;

    int ncells = in_sizes[0] / 30;  // 802816

    hipMemsetAsync(d_out, 0, sizeof(float), stream);

    int grid = (ncells + TILE - 1) / TILE;  // 3136
    yolo_loss_kernel<<<grid, 256, 0, stream>>>(preds, targets, out, ncells);
}